// Round 14
// baseline (139.565 us; speedup 1.0000x reference)
//
#include <hip/hip_runtime.h>
#include <math.h>

#define SLEN 4096
#define DM   768
#define NH   12
#define DKH  64

typedef unsigned short u16;
typedef unsigned int   u32;
typedef __attribute__((ext_vector_type(8))) short short8;   // 8 x bf16 bits
typedef __attribute__((ext_vector_type(4))) float f32x4;
typedef __attribute__((ext_vector_type(2))) unsigned int u32x2;
typedef __attribute__((ext_vector_type(4))) unsigned int u32x4;
typedef __attribute__((address_space(1))) const void gconst_void;
typedef __attribute__((address_space(3))) void lds_void;

__device__ __forceinline__ u16 f2bf(float f) {
    unsigned u = __builtin_bit_cast(unsigned, f);
    u += 0x7fffu + ((u >> 16) & 1u);            // RNE
    return (u16)(u >> 16);
}
__device__ __forceinline__ u32 cvtpk(float a, float b) {   // 2xbf16 in one op
    u32 r;
    asm("v_cvt_pk_bf16_f32 %0, %1, %2" : "=v"(r) : "v"(a), "v"(b));
    return r;
}
__device__ __forceinline__ u32 pkh2(float a, float b) {    // 2xf16 (RTZ)
    u32 r;
    asm("v_cvt_pkrtz_f16_f32 %0, %1, %2" : "=v"(r) : "v"(a), "v"(b));
    return r;
}
__device__ __forceinline__ void gload16(const u16* src, void* lds) {
    __builtin_amdgcn_global_load_lds((gconst_void*)src, (lds_void*)lds, 16, 0, 0);
}

// ---------------------------------------------------------------------------
// prep: cast x + 4 weights to bf16, build rope table tab[pos][pk] = (cos,sin)
// ---------------------------------------------------------------------------
__global__ __launch_bounds__(256)
void prep_kernel(const float* __restrict__ x,  const float* __restrict__ wq,
                 const float* __restrict__ wk, const float* __restrict__ wv,
                 const float* __restrict__ wo, const int* __restrict__ pos,
                 u16* __restrict__ cx,  u16* __restrict__ cwq, u16* __restrict__ cwk,
                 u16* __restrict__ cwv, u16* __restrict__ cwo, float2* __restrict__ tab)
{
    const int tid = blockIdx.x * 256 + threadIdx.x;
    const int NX = SLEN * DM / 4;     // quads of x
    const int NW = DM * DM / 4;       // quads per weight
    if (tid < NX + 4 * NW) {
        const float* s; u16* d; int i;
        if (tid < NX) { s = x; d = cx; i = tid; }
        else {
            int t2 = tid - NX; int seg = t2 / NW; i = t2 - seg * NW;
            s = (seg == 0) ? wq : (seg == 1) ? wk : (seg == 2) ? wv : wo;
            d = (seg == 0) ? cwq : (seg == 1) ? cwk : (seg == 2) ? cwv : cwo;
        }
        float4 v = *reinterpret_cast<const float4*>(s + (size_t)i * 4);
        u16* o = d + (size_t)i * 4;
        o[0] = f2bf(v.x); o[1] = f2bf(v.y); o[2] = f2bf(v.z); o[3] = f2bf(v.w);
    } else {
        int t2 = tid - (NX + 4 * NW);
        if (t2 < SLEN * 32) {
            int p = t2 >> 5, k = t2 & 31;
            const float invf = __builtin_amdgcn_exp2f((float)k * -0.41524101f);
            float ang = (float)pos[p] * invf;
            float sn, cs;
            __sincosf(ang, &sn, &cs);
            tab[t2] = make_float2(cs, sn);
        }
    }
}

// ---------------------------------------------------------------------------
// FUSED QKV GEMM: one block computes Q,K,V 64x128 tiles for (m0,n0), sharing
// the X (As) tile across all three: per k-step 7 gload_lds + 24 MFMA
// (vs 3 kernels x (3 gload + 8 MFMA)). R8 2-barrier counted-vmcnt skeleton.
// Epilogues: Q = rope*0.125*log2e -> bf16; K = rope -> bf16; V -> V^T [o][s].
// LDS 56KB (2 blocks/CU). Grid (64, 6).
// ---------------------------------------------------------------------------
__global__ __launch_bounds__(256)
void gemm_qkv(const u16* __restrict__ X,
              const u16* __restrict__ Wq, const u16* __restrict__ Wk,
              const u16* __restrict__ Wv, const float2* __restrict__ tab,
              u16* __restrict__ Oq, u16* __restrict__ Ok, u16* __restrict__ OVt)
{
    __shared__ u16 As[2][64 * 32];    // 2 x 4 KB
    __shared__ u16 Bs[3][2][128 * 32];// 3 x 2 x 8 KB

    const int tid = threadIdx.x;
    const int l = tid & 63, wvid = tid >> 6;
    const int g = l >> 4, lq = l & 15;
    const int wm = wvid >> 1, wn = wvid & 1;
    const int m0 = blockIdx.x * 64, n0 = blockIdx.y * 128;

    const u16* W[3] = {Wq, Wk, Wv};

    const int srow0 = wvid * 16 + (l >> 2);   // staging row 0..63
    const int sslot = l & 3;
    const int sss = sslot ^ ((srow0 >> 1) & 3);
    const int sss2 = sslot ^ (((64 + srow0) >> 1) & 3);

    f32x4 acc[3][2][4];
#pragma unroll
    for (int m = 0; m < 3; ++m)
#pragma unroll
        for (int a = 0; a < 2; ++a)
#pragma unroll
            for (int b = 0; b < 4; ++b) acc[m][a][b] = (f32x4){0.f, 0.f, 0.f, 0.f};

    // prologue: stage k0=0 into buf 0 (7 loads/thread)
    gload16(X + (size_t)(m0 + srow0) * DM + sss * 8, (char*)As[0] + wvid * 1024);
#pragma unroll
    for (int m = 0; m < 3; ++m) {
        gload16(W[m] + (size_t)(n0 + srow0) * DM + sss * 8, (char*)Bs[m][0] + wvid * 1024);
        gload16(W[m] + (size_t)(n0 + 64 + srow0) * DM + sss2 * 8, (char*)Bs[m][0] + 4096 + wvid * 1024);
    }
    __syncthreads();

    for (int k0 = 0, it = 0; k0 < DM; k0 += 32, ++it) {
        const int cur = it & 1, nxt = cur ^ 1;
        const bool pre = (k0 + 32 < DM);
        if (pre) {
            const int kn = k0 + 32;
            gload16(X + (size_t)(m0 + srow0) * DM + kn + sss * 8, (char*)As[nxt] + wvid * 1024);
#pragma unroll
            for (int m = 0; m < 3; ++m) {
                gload16(W[m] + (size_t)(n0 + srow0) * DM + kn + sss * 8, (char*)Bs[m][nxt] + wvid * 1024);
                gload16(W[m] + (size_t)(n0 + 64 + srow0) * DM + kn + sss2 * 8, (char*)Bs[m][nxt] + 4096 + wvid * 1024);
            }
            asm volatile("s_waitcnt vmcnt(7)" ::: "memory");
        } else {
            asm volatile("s_waitcnt vmcnt(0)" ::: "memory");
        }
        __builtin_amdgcn_s_barrier();

        short8 af[2];
#pragma unroll
        for (int mf = 0; mf < 2; ++mf) {
            const int r = wm * 32 + mf * 16 + lq;
            const int sl = g ^ ((r >> 1) & 3);
            af[mf] = *(const short8*)((const char*)As[cur] + r * 64 + sl * 16);
        }
#pragma unroll
        for (int m = 0; m < 3; ++m) {
            short8 bfr[4];
#pragma unroll
            for (int nf = 0; nf < 4; ++nf) {
                const int r = wn * 64 + nf * 16 + lq;
                const int sl = g ^ ((r >> 1) & 3);
                bfr[nf] = *(const short8*)((const char*)Bs[m][cur] + r * 64 + sl * 16);
            }
#pragma unroll
            for (int mf = 0; mf < 2; ++mf)
#pragma unroll
                for (int nf = 0; nf < 4; ++nf)
                    acc[m][mf][nf] = __builtin_amdgcn_mfma_f32_16x16x32_bf16(af[mf], bfr[nf], acc[m][mf][nf], 0, 0, 0);
        }
        if (pre) __builtin_amdgcn_s_barrier();
    }

    // epilogues: C/D layout col=l&15, row=(l>>4)*4+reg
#pragma unroll
    for (int m = 0; m < 3; ++m) {
#pragma unroll
        for (int nf = 0; nf < 4; ++nf) {
            const int col = n0 + wn * 64 + nf * 16 + lq;
            const int pk = (col & 63) >> 1;
            const bool even = (col & 1) == 0;
#pragma unroll
            for (int mf = 0; mf < 2; ++mf) {
                const int row0 = m0 + wm * 32 + mf * 16 + g * 4;
                if (m == 2) {
                    // V: transposed store OVt[col][row0..+3]
                    u32x2 w;
                    w.x = cvtpk(acc[2][mf][nf][0], acc[2][mf][nf][1]);
                    w.y = cvtpk(acc[2][mf][nf][2], acc[2][mf][nf][3]);
                    *(u32x2*)&OVt[(size_t)col * SLEN + row0] = w;
                    continue;
                }
#pragma unroll
                for (int r = 0; r < 4; ++r) {
                    const int row = row0 + r;
                    float v = acc[m][mf][nf][r];
                    float p = __shfl_xor(v, 1, 64);          // partner col (l^1)
                    float2 cs = tab[row * 32 + pk];
                    float x1 = even ? v : p;
                    float x2 = even ? p : v;
                    float o = even ? x1 * cs.x - x2 * cs.y
                                   : x1 * cs.y + x2 * cs.x;
                    if (m == 0) o *= 0.18033688f;            // (1/8)*log2(e)
                    u16* dst = (m == 0) ? Oq : Ok;
                    dst[(size_t)row * DM + col] = f2bf(o);
                }
            }
        }
    }
}

// ---------------------------------------------------------------------------
// bf16 MFMA GEMM (O-projection): OUT[s][o] = sum_d A[s][d]*B[o][d], f32 out.
// 64x128 tile, BK=32, R8 2-barrier counted-vmcnt pipeline.
// ---------------------------------------------------------------------------
__global__ __launch_bounds__(256)
void gemm_out(const u16* __restrict__ Ain, const u16* __restrict__ B,
              float* __restrict__ OF)
{
    __shared__ u16 As[2][64 * 32];    // 2 x 4 KB
    __shared__ u16 Bs[2][128 * 32];   // 2 x 8 KB

    const int tid = threadIdx.x;
    const int l = tid & 63, wvid = tid >> 6;
    const int g = l >> 4, lq = l & 15;
    const int wm = wvid >> 1, wn = wvid & 1;
    const int m0 = blockIdx.x * 64, n0 = blockIdx.y * 128;

    const int srow0 = wvid * 16 + (l >> 2);   // staging row 0..63
    const int sslot = l & 3;
    const int sss = sslot ^ ((srow0 >> 1) & 3);
    const int sss2 = sslot ^ (((64 + srow0) >> 1) & 3);

    f32x4 acc[2][4];
#pragma unroll
    for (int a = 0; a < 2; ++a)
#pragma unroll
        for (int b = 0; b < 4; ++b) acc[a][b] = (f32x4){0.f, 0.f, 0.f, 0.f};

    // prologue: stage k0=0 into buf 0
    gload16(Ain + (size_t)(m0 + srow0) * DM + sss * 8, (char*)As[0] + wvid * 1024);
    gload16(B + (size_t)(n0 + srow0) * DM + sss * 8, (char*)Bs[0] + wvid * 1024);
    gload16(B + (size_t)(n0 + 64 + srow0) * DM + sss2 * 8, (char*)Bs[0] + 4096 + wvid * 1024);
    __syncthreads();

    for (int k0 = 0, it = 0; k0 < DM; k0 += 32, ++it) {
        const int cur = it & 1, nxt = cur ^ 1;
        const bool pre = (k0 + 32 < DM);
        if (pre) {
            const int kn = k0 + 32;
            gload16(Ain + (size_t)(m0 + srow0) * DM + kn + sss * 8, (char*)As[nxt] + wvid * 1024);
            gload16(B + (size_t)(n0 + srow0) * DM + kn + sss * 8, (char*)Bs[nxt] + wvid * 1024);
            gload16(B + (size_t)(n0 + 64 + srow0) * DM + kn + sss2 * 8, (char*)Bs[nxt] + 4096 + wvid * 1024);
            asm volatile("s_waitcnt vmcnt(3)" ::: "memory");
        } else {
            asm volatile("s_waitcnt vmcnt(0)" ::: "memory");
        }
        __builtin_amdgcn_s_barrier();

        short8 af[2], bfr[4];
#pragma unroll
        for (int mf = 0; mf < 2; ++mf) {
            const int r = wm * 32 + mf * 16 + lq;
            const int sl = g ^ ((r >> 1) & 3);
            af[mf] = *(const short8*)((const char*)As[cur] + r * 64 + sl * 16);
        }
#pragma unroll
        for (int nf = 0; nf < 4; ++nf) {
            const int r = wn * 64 + nf * 16 + lq;
            const int sl = g ^ ((r >> 1) & 3);
            bfr[nf] = *(const short8*)((const char*)Bs[cur] + r * 64 + sl * 16);
        }
#pragma unroll
        for (int mf = 0; mf < 2; ++mf)
#pragma unroll
            for (int nf = 0; nf < 4; ++nf)
                acc[mf][nf] = __builtin_amdgcn_mfma_f32_16x16x32_bf16(af[mf], bfr[nf], acc[mf][nf], 0, 0, 0);
        if (pre) __builtin_amdgcn_s_barrier();
    }

    // epilogue: f32 store
#pragma unroll
    for (int nf = 0; nf < 4; ++nf) {
        const int col = n0 + wn * 64 + nf * 16 + lq;
#pragma unroll
        for (int mf = 0; mf < 2; ++mf) {
            const int row0 = m0 + wm * 32 + mf * 16 + g * 4;
#pragma unroll
            for (int r = 0; r < 4; ++r)
                OF[(size_t)(row0 + r) * DM + col] = acc[mf][nf][r];
        }
    }
}

// ---------------------------------------------------------------------------
// MFMA flash attention (causal), swapped orientation, 64-q blocks, kv-split,
// single barrier/tile, P entirely in registers (permlane 4x4 g-transpose).
// S^T = mfma(A=K, B=Q), O^T = mfma(A=V^T, B=P^T); lane owns q-col.
// Softmax p = exp2(s) unscaled (cancels in normalize); lr per-lane.
// bid<768: qb 32..63 split in 2 kv-chunks -> f16 partials + l; else direct.
// ---------------------------------------------------------------------------
__global__ __launch_bounds__(256)
void attn_mfma(const u16* __restrict__ Q, const u16* __restrict__ K,
               const u16* __restrict__ VT, u16* __restrict__ A,
               u16* __restrict__ Opart, float* __restrict__ ML)
{
    __shared__ u16 Ks[2][64 * 64];   // [kv][d] rows 128B, slot-swizzled, 16KB
    __shared__ u16 Vt[2][64 * 64];   // [d][kv] rows 128B, slot-swizzled, 16KB

    const int tid = threadIdx.x;
    const int l = tid & 63, wid = tid >> 6;
    const int g = l >> 4, lq = l & 15;
    const int bid = blockIdx.x;

    int qb, h, tstart, tend, pi;
    if (bid < 768) {                       // split blocks, longest first
        const int pairIdx = bid >> 1, chunk = bid & 1;
        qb = 63 - pairIdx / NH;
        h  = pairIdx % NH;
        const int nt = qb + 1, nh0 = nt >> 1;
        tstart = chunk ? nh0 : 0;
        tend   = chunk ? nt : nh0;
        pi = ((qb - 32) * NH + h) * 2 + chunk;
    } else {                               // direct blocks
        const int idx = bid - 768;
        qb = 31 - idx / NH;
        h  = idx % NH;
        tstart = 0; tend = qb + 1;
        pi = -1;
    }
    const int q0 = qb * 64;
    const int hc = h * DKH;
    const int ntg = qb + 1;                // global tile count (diagonal id)

    // staging geometry (loop-invariant)
    const int srow = wid * 8 + (l >> 3);           // 0..31 (row within half)
    const int sss  = (l & 7) ^ (srow & 7);         // swizzled slot

    // hoist Q as B-frags: col q = lq, k d = kf*32 + g*8
    short8 qf[2];
#pragma unroll
    for (int kf = 0; kf < 2; ++kf)
        qf[kf] = *(const short8*)&Q[(size_t)(q0 + wid * 16 + lq) * DM + hc + kf * 32 + g * 8];

    f32x4 oacc[4];
    float lr = 0.f;                        // per-lane partial sum
#pragma unroll
    for (int nf = 0; nf < 4; ++nf) oacc[nf] = (f32x4){0.f, 0.f, 0.f, 0.f};

    // ---- prologue: issue tile tstart into buffer 0 (K and V^T) ----
    {
        const int k0 = tstart * 64;
#pragma unroll
        for (int u = 0; u < 2; ++u) {
            const int row = u * 32 + srow;
            gload16(K + (size_t)(k0 + row) * DM + hc + sss * 8,
                    (char*)Ks[0] + u * 4096 + wid * 1024);
            gload16(VT + (size_t)(hc + row) * SLEN + k0 + sss * 8,
                    (char*)Vt[0] + u * 4096 + wid * 1024);
        }
    }

    for (int t = tstart; t < tend; ++t) {
        const int cur = (t - tstart) & 1, nxt = cur ^ 1;
        const int k0 = t * 64;

        asm volatile("s_waitcnt vmcnt(0)" ::: "memory");   // my cur-tile loads done
        __builtin_amdgcn_s_barrier();                      // => all waves' loads done

        // nxt buffer provably dead now: issue next tile (lands under compute)
        if (t + 1 < tend) {
            const int k0n = k0 + 64;
#pragma unroll
            for (int u = 0; u < 2; ++u) {
                const int row = u * 32 + srow;
                gload16(K + (size_t)(k0n + row) * DM + hc + sss * 8,
                        (char*)Ks[nxt] + u * 4096 + wid * 1024);
                gload16(VT + (size_t)(hc + row) * SLEN + k0n + sss * 8,
                        (char*)Vt[nxt] + u * 4096 + wid * 1024);
            }
        }

        // S^T = K * Q^T : lane q = lq, kv = cf*16 + 4g + r
        f32x4 st[4];
#pragma unroll
        for (int cf = 0; cf < 4; ++cf) st[cf] = (f32x4){0.f, 0.f, 0.f, 0.f};

        __builtin_amdgcn_s_setprio(1);
#pragma unroll
        for (int cf = 0; cf < 4; ++cf) {
            const int row = cf * 16 + lq;
            const short8 ak0 = *(const short8*)((const char*)Ks[cur] + row * 128 + ((g)     ^ (row & 7)) * 16);
            const short8 ak1 = *(const short8*)((const char*)Ks[cur] + row * 128 + ((4 + g) ^ (row & 7)) * 16);
            st[cf] = __builtin_amdgcn_mfma_f32_16x16x32_bf16(ak0, qf[0], st[cf], 0, 0, 0);
            st[cf] = __builtin_amdgcn_mfma_f32_16x16x32_bf16(ak1, qf[1], st[cf], 0, 0, 0);
        }
        __builtin_amdgcn_s_setprio(0);

        // causal mask: only the global diagonal tile
        if (t == ntg - 1) {
            const int qg = q0 + wid * 16 + lq;
#pragma unroll
            for (int cf = 0; cf < 4; ++cf)
#pragma unroll
                for (int r = 0; r < 4; ++r)
                    if (k0 + cf * 16 + g * 4 + r > qg) st[cf][r] = -INFINITY;
        }

        // softmax: p = exp2(s) unscaled (2^m factor cancels in normalize)
#pragma unroll
        for (int cf = 0; cf < 4; ++cf)
#pragma unroll
            for (int r = 0; r < 4; ++r) {
                const float p = __builtin_amdgcn_exp2f(st[cf][r]);
                st[cf][r] = p;
                lr += p;
            }

        // pack P: wx[cf] = bf16pair(kv 16cf+4g+{0,1}), wy[cf] = (+{2,3})
        u32 wx[4], wy[4];
#pragma unroll
        for (int cf = 0; cf < 4; ++cf) {
            wx[cf] = cvtpk(st[cf][0], st[cf][1]);
            wy[cf] = cvtpk(st[cf][2], st[cf][3]);
        }

        // in-register P^T -> PV B-frag: 4x4 g-group transpose via permlane
        short8 pbf[2];
#pragma unroll
        for (int kf = 0; kf < 2; ++kf) {
            u32 x0 = wx[2 * kf], y0 = wx[2 * kf + 1];
            asm volatile("v_permlane32_swap_b32 %0, %1" : "+v"(x0), "+v"(y0));
            asm volatile("v_permlane16_swap_b32 %0, %1" : "+v"(x0), "+v"(y0));
            u32 x1 = wy[2 * kf], y1 = wy[2 * kf + 1];
            asm volatile("v_permlane32_swap_b32 %0, %1" : "+v"(x1), "+v"(y1));
            asm volatile("v_permlane16_swap_b32 %0, %1" : "+v"(x1), "+v"(y1));
            u32x4 bv;
            bv.x = x0; bv.y = x1; bv.z = y0; bv.w = y1;
            pbf[kf] = __builtin_bit_cast(short8, bv);
        }

        // O^T += V^T * P^T
        __builtin_amdgcn_s_setprio(1);
#pragma unroll
        for (int kf = 0; kf < 2; ++kf)
#pragma unroll
            for (int nf = 0; nf < 4; ++nf) {
                const int row = nf * 16 + lq;
                const short8 av = *(const short8*)((const char*)Vt[cur] + row * 128 + ((kf * 4 + g) ^ (row & 7)) * 16);
                oacc[nf] = __builtin_amdgcn_mfma_f32_16x16x32_bf16(av, pbf[kf], oacc[nf], 0, 0, 0);
            }
        __builtin_amdgcn_s_setprio(0);
    }

    // epilogue: reduce lr across the 4 g-groups once, then store
    lr += __shfl_xor(lr, 16, 64);
    lr += __shfl_xor(lr, 32, 64);
    const float inv = 1.0f / lr;
    const int qloc = wid * 16 + lq;
    if (pi < 0) {
        // direct: O = O^T / l -> A (bf16)
        const int qg = q0 + qloc;
#pragma unroll
        for (int nf = 0; nf < 4; ++nf) {
            u32x2 w;
            w.x = cvtpk(oacc[nf][0] * inv, oacc[nf][1] * inv);
            w.y = cvtpk(oacc[nf][2] * inv, oacc[nf][3] * inv);
            *(u32x2*)&A[(size_t)qg * DM + hc + nf * 16 + g * 4] = w;
        }
    } else {
        // split: normalized partial O (f16) + l
        u16* op = Opart + (size_t)pi * 4096 + qloc * 64;
#pragma unroll
        for (int nf = 0; nf < 4; ++nf) {
            u32x2 w;
            w.x = pkh2(oacc[nf][0] * inv, oacc[nf][1] * inv);
            w.y = pkh2(oacc[nf][2] * inv, oacc[nf][3] * inv);
            *(u32x2*)&op[nf * 16 + g * 4] = w;
        }
        if (g == 0) ML[pi * 64 + qloc] = lr;
    }
}

// ---------------------------------------------------------------------------
// combine: merge the 2 kv-chunk partials for qb in [32,63]. Same (implicit)
// max on both chunks -> weights are pure l-ratios.
// 384 blocks x 256 thr; thread = (q = tid>>2, 16 d's at (tid&3)*16).
// ---------------------------------------------------------------------------
__global__ __launch_bounds__(256)
void attn_combine(const u16* __restrict__ Opart, const float* __restrict__ ML,
                  u16* __restrict__ A)
{
    const int bi = blockIdx.x;
    const int qb = 32 + bi / NH, h = bi % NH;
    const int base = ((qb - 32) * NH + h) * 2;
    const int q = threadIdx.x >> 2, db = (threadIdx.x & 3) * 16;

    const float l0 = ML[base * 64 + q];
    const float l1 = ML[base * 64 + 64 + q];
    const float inv = 1.0f / (l0 + l1);
    const float w0 = l0 * inv, w1 = l1 * inv;

    const _Float16* O0 = (const _Float16*)(Opart + (size_t)base * 4096) + q * 64 + db;
    const _Float16* O1 = O0 + 4096;
    u16* dst = A + (size_t)(qb * 64 + q) * DM + h * DKH + db;

    u32 wbuf[8];
#pragma unroll
    for (int j = 0; j < 8; ++j) {
        const float v0 = w0 * (float)O0[2 * j]     + w1 * (float)O1[2 * j];
        const float v1 = w0 * (float)O0[2 * j + 1] + w1 * (float)O1[2 * j + 1];
        wbuf[j] = cvtpk(v0, v1);
    }
#pragma unroll
    for (int j = 0; j < 4; ++j)
        *(u32x2*)&dst[j * 4] = (u32x2){wbuf[2 * j], wbuf[2 * j + 1]};
}

extern "C" void kernel_launch(void* const* d_in, const int* in_sizes, int n_in,
                              void* d_out, int out_size, void* d_ws, size_t ws_size,
                              hipStream_t stream)
{
    const float* x  = (const float*)d_in[0];
    const float* wq = (const float*)d_in[1];
    const float* wk = (const float*)d_in[2];
    const float* wv = (const float*)d_in[3];
    const float* wo = (const float*)d_in[4];
    const int*  pos = (const int*)d_in[5];
    float* out = (float*)d_out;

    const size_t SD = (size_t)SLEN * DM;   // 3145728
    const size_t WW = (size_t)DM * DM;     // 589824
    if (ws_size < ((SD * 5 + WW * 4) * 2 + (size_t)SLEN * 32 * 8 + 1024)) return;

    u16* cx  = (u16*)d_ws;
    u16* cwq = cx  + SD;
    u16* cwk = cwq + WW;
    u16* cwv = cwk + WW;
    u16* cwo = cwv + WW;
    u16* qb_ = cwo + WW;
    u16* kb_ = qb_ + SD;
    u16* vb_ = kb_ + SD;     // V^T: [DM][SLEN]
    u16* ab_ = vb_ + SD;
    float2* tab = (float2*)(ab_ + SD);

    // partials reuse regions dead after gemm_qkv: Opart in cx (exactly SD u16),
    // ML in cwq (768*64*4B = 196KB < WW*2B).
    u16*   opart = cx;
    float* ml    = (float*)cwq;

    prep_kernel<<<5888, 256, 0, stream>>>(x, wq, wk, wv, wo, pos,
                                          cx, cwq, cwk, cwv, cwo, tab);

    dim3 g1(SLEN / 64, DM / 128);
    gemm_qkv<<<g1, 256, 0, stream>>>(cx, cwq, cwk, cwv, tab, qb_, kb_, vb_);

    attn_mfma<<<dim3(1152), 256, 0, stream>>>(qb_, kb_, vb_, ab_, opart, ml);
    attn_combine<<<dim3(384), 256, 0, stream>>>(opart, ml, ab_);

    dim3 g3(SLEN / 64, DM / 128);
    gemm_out<<<g3, 256, 0, stream>>>(ab_, cwo, out);
}

// Round 15
// 116.967 us; speedup vs baseline: 1.1932x; 1.1932x over previous
//
#include <hip/hip_runtime.h>
#include <math.h>

#define SLEN 4096
#define DM   768
#define NH   12
#define DKH  64

typedef unsigned short u16;
typedef unsigned int   u32;
typedef __attribute__((ext_vector_type(8))) short short8;   // 8 x bf16 bits
typedef __attribute__((ext_vector_type(4))) float f32x4;
typedef __attribute__((ext_vector_type(2))) unsigned int u32x2;
typedef __attribute__((ext_vector_type(4))) unsigned int u32x4;
typedef __attribute__((address_space(1))) const void gconst_void;
typedef __attribute__((address_space(3))) void lds_void;

__device__ __forceinline__ u16 f2bf(float f) {
    unsigned u = __builtin_bit_cast(unsigned, f);
    u += 0x7fffu + ((u >> 16) & 1u);            // RNE
    return (u16)(u >> 16);
}
__device__ __forceinline__ u32 cvtpk(float a, float b) {   // 2xbf16 in one op
    u32 r;
    asm("v_cvt_pk_bf16_f32 %0, %1, %2" : "=v"(r) : "v"(a), "v"(b));
    return r;
}
__device__ __forceinline__ u32 pkh2(float a, float b) {    // 2xf16 (RTZ)
    u32 r;
    asm("v_cvt_pkrtz_f16_f32 %0, %1, %2" : "=v"(r) : "v"(a), "v"(b));
    return r;
}
__device__ __forceinline__ void gload16(const u16* src, void* lds) {
    __builtin_amdgcn_global_load_lds((gconst_void*)src, (lds_void*)lds, 16, 0, 0);
}

// ---------------------------------------------------------------------------
// prep: cast x + 4 weights to bf16, build rope table tab[pos][pk] = (cos,sin)
// fast trig: inv_freq via exp2f, hardware __sincosf (err ~4e-4 rad << bf16)
// ---------------------------------------------------------------------------
__global__ __launch_bounds__(256)
void prep_kernel(const float* __restrict__ x,  const float* __restrict__ wq,
                 const float* __restrict__ wk, const float* __restrict__ wv,
                 const float* __restrict__ wo, const int* __restrict__ pos,
                 u16* __restrict__ cx,  u16* __restrict__ cwq, u16* __restrict__ cwk,
                 u16* __restrict__ cwv, u16* __restrict__ cwo, float2* __restrict__ tab)
{
    const int tid = blockIdx.x * 256 + threadIdx.x;
    const int NX = SLEN * DM / 4;     // quads of x
    const int NW = DM * DM / 4;       // quads per weight
    if (tid < NX + 4 * NW) {
        const float* s; u16* d; int i;
        if (tid < NX) { s = x; d = cx; i = tid; }
        else {
            int t2 = tid - NX; int seg = t2 / NW; i = t2 - seg * NW;
            s = (seg == 0) ? wq : (seg == 1) ? wk : (seg == 2) ? wv : wo;
            d = (seg == 0) ? cwq : (seg == 1) ? cwk : (seg == 2) ? cwv : cwo;
        }
        float4 v = *reinterpret_cast<const float4*>(s + (size_t)i * 4);
        u16* o = d + (size_t)i * 4;
        o[0] = f2bf(v.x); o[1] = f2bf(v.y); o[2] = f2bf(v.z); o[3] = f2bf(v.w);
    } else {
        int t2 = tid - (NX + 4 * NW);
        if (t2 < SLEN * 32) {
            int p = t2 >> 5, k = t2 & 31;
            // 10000^(-k/32) = 2^(-k*log2(1e4)/32), log2(1e4)/32 = 0.41524101
            const float invf = __builtin_amdgcn_exp2f((float)k * -0.41524101f);
            float ang = (float)pos[p] * invf;
            float sn, cs;
            __sincosf(ang, &sn, &cs);
            tab[t2] = make_float2(cs, sn);
        }
    }
}

// ---------------------------------------------------------------------------
// bf16 MFMA GEMM (R8 form — best measured): OUT[s][o] = sum_d A[s][d]*B[o][d].
// 64x128 tile, BK=32, 4 waves (2x2), 2x4 frags/wave. 2-phase counted-vmcnt:
//   stage buf[nxt] -> vmcnt(3) -> s_barrier -> compute buf[cur] -> s_barrier
// mode: 0=Q(rope,*0.125*log2e) 1=K(rope) 2=V TRANSPOSED [o][s] 3=f32 out.
// ---------------------------------------------------------------------------
__global__ __launch_bounds__(256)
void gemm_bf16(const u16* __restrict__ Ain,
               const u16* __restrict__ B0, const u16* __restrict__ B1,
               const u16* __restrict__ B2, const float2* __restrict__ tab,
               u16* __restrict__ O0, u16* __restrict__ O1, u16* __restrict__ O2,
               float* __restrict__ OF, int modeBase)
{
    __shared__ u16 As[2][64 * 32];    // 2 x 4 KB
    __shared__ u16 Bs[2][128 * 32];   // 2 x 8 KB

    const int tid = threadIdx.x;
    const int l = tid & 63, wvid = tid >> 6;
    const int g = l >> 4, lq = l & 15;
    const int wm = wvid >> 1, wn = wvid & 1;
    const int m0 = blockIdx.x * 64, n0 = blockIdx.y * 128;
    const int z = blockIdx.z;
    const int mode = (modeBase == 3) ? 3 : z;
    const u16* B = (z == 0) ? B0 : (z == 1) ? B1 : B2;
    u16* OU      = (z == 0) ? O0 : (z == 1) ? O1 : O2;

    const int srow0 = wvid * 16 + (l >> 2);   // staging row 0..63
    const int sslot = l & 3;
    const int sss = sslot ^ ((srow0 >> 1) & 3);
    const int sss2 = sslot ^ (((64 + srow0) >> 1) & 3);

    f32x4 acc[2][4];
#pragma unroll
    for (int a = 0; a < 2; ++a)
#pragma unroll
        for (int b = 0; b < 4; ++b) acc[a][b] = (f32x4){0.f, 0.f, 0.f, 0.f};

    // prologue: stage k0=0 into buf 0
    gload16(Ain + (size_t)(m0 + srow0) * DM + sss * 8, (char*)As[0] + wvid * 1024);
    gload16(B + (size_t)(n0 + srow0) * DM + sss * 8, (char*)Bs[0] + wvid * 1024);
    gload16(B + (size_t)(n0 + 64 + srow0) * DM + sss2 * 8, (char*)Bs[0] + 4096 + wvid * 1024);
    __syncthreads();

    for (int k0 = 0, it = 0; k0 < DM; k0 += 32, ++it) {
        const int cur = it & 1, nxt = cur ^ 1;
        const bool pre = (k0 + 32 < DM);
        if (pre) {
            const int kn = k0 + 32;
            gload16(Ain + (size_t)(m0 + srow0) * DM + kn + sss * 8, (char*)As[nxt] + wvid * 1024);
            gload16(B + (size_t)(n0 + srow0) * DM + kn + sss * 8, (char*)Bs[nxt] + wvid * 1024);
            gload16(B + (size_t)(n0 + 64 + srow0) * DM + kn + sss2 * 8, (char*)Bs[nxt] + 4096 + wvid * 1024);
            asm volatile("s_waitcnt vmcnt(3)" ::: "memory");
        } else {
            asm volatile("s_waitcnt vmcnt(0)" ::: "memory");
        }
        __builtin_amdgcn_s_barrier();

        short8 af[2], bfr[4];
#pragma unroll
        for (int mf = 0; mf < 2; ++mf) {
            const int r = wm * 32 + mf * 16 + lq;
            const int sl = g ^ ((r >> 1) & 3);
            af[mf] = *(const short8*)((const char*)As[cur] + r * 64 + sl * 16);
        }
#pragma unroll
        for (int nf = 0; nf < 4; ++nf) {
            const int r = wn * 64 + nf * 16 + lq;
            const int sl = g ^ ((r >> 1) & 3);
            bfr[nf] = *(const short8*)((const char*)Bs[cur] + r * 64 + sl * 16);
        }
#pragma unroll
        for (int mf = 0; mf < 2; ++mf)
#pragma unroll
            for (int nf = 0; nf < 4; ++nf)
                acc[mf][nf] = __builtin_amdgcn_mfma_f32_16x16x32_bf16(af[mf], bfr[nf], acc[mf][nf], 0, 0, 0);
        if (pre) __builtin_amdgcn_s_barrier();
    }

    // epilogue: C/D layout col=l&15, row=(l>>4)*4+reg
#pragma unroll
    for (int nf = 0; nf < 4; ++nf) {
        const int col = n0 + wn * 64 + nf * 16 + lq;
        const int pk = (col & 63) >> 1;
        const bool even = (col & 1) == 0;
#pragma unroll
        for (int mf = 0; mf < 2; ++mf) {
            const int row0 = m0 + wm * 32 + mf * 16 + g * 4;
            if (mode == 2) {
                // transposed store: VT[col][row0..row0+3], 4 bf16 = 8B
                u32x2 w;
                w.x = cvtpk(acc[mf][nf][0], acc[mf][nf][1]);
                w.y = cvtpk(acc[mf][nf][2], acc[mf][nf][3]);
                *(u32x2*)&OU[(size_t)col * SLEN + row0] = w;
                continue;
            }
#pragma unroll
            for (int r = 0; r < 4; ++r) {
                const int row = row0 + r;
                float v = acc[mf][nf][r];
                if (mode <= 1) {
                    float p = __shfl_xor(v, 1, 64);          // partner col (l^1)
                    float2 cs = tab[row * 32 + pk];
                    float x1 = even ? v : p;
                    float x2 = even ? p : v;
                    float o = even ? x1 * cs.x - x2 * cs.y
                                   : x1 * cs.y + x2 * cs.x;
                    if (mode == 0) o *= 0.18033688f;         // (1/8)*log2(e): exp2 softmax
                    OU[(size_t)row * DM + col] = f2bf(o);
                } else {
                    OF[(size_t)row * DM + col] = v;
                }
            }
        }
    }
}

// ---------------------------------------------------------------------------
// MFMA flash attention (R13 form — best measured): causal, swapped
// orientation, 64-q blocks, kv-split, single barrier/tile, P entirely in
// registers via permlane 4x4 g-group transpose (0 bank conflicts, VGPR 44).
// S^T = mfma(A=K, B=Q), O^T = mfma(A=V^T, B=P^T); lane owns q-col.
// Softmax p = exp2(s) unscaled (cancels in normalize); lr per-lane.
// bid<768: qb 32..63 split in 2 kv-chunks -> f16 partials + l; else direct.
// ---------------------------------------------------------------------------
__global__ __launch_bounds__(256)
void attn_mfma(const u16* __restrict__ Q, const u16* __restrict__ K,
               const u16* __restrict__ VT, u16* __restrict__ A,
               u16* __restrict__ Opart, float* __restrict__ ML)
{
    __shared__ u16 Ks[2][64 * 64];   // [kv][d] rows 128B, slot-swizzled, 16KB
    __shared__ u16 Vt[2][64 * 64];   // [d][kv] rows 128B, slot-swizzled, 16KB

    const int tid = threadIdx.x;
    const int l = tid & 63, wid = tid >> 6;
    const int g = l >> 4, lq = l & 15;
    const int bid = blockIdx.x;

    int qb, h, tstart, tend, pi;
    if (bid < 768) {                       // split blocks, longest first
        const int pairIdx = bid >> 1, chunk = bid & 1;
        qb = 63 - pairIdx / NH;
        h  = pairIdx % NH;
        const int nt = qb + 1, nh0 = nt >> 1;
        tstart = chunk ? nh0 : 0;
        tend   = chunk ? nt : nh0;
        pi = ((qb - 32) * NH + h) * 2 + chunk;
    } else {                               // direct blocks
        const int idx = bid - 768;
        qb = 31 - idx / NH;
        h  = idx % NH;
        tstart = 0; tend = qb + 1;
        pi = -1;
    }
    const int q0 = qb * 64;
    const int hc = h * DKH;
    const int ntg = qb + 1;                // global tile count (diagonal id)

    // staging geometry (loop-invariant)
    const int srow = wid * 8 + (l >> 3);           // 0..31 (row within half)
    const int sss  = (l & 7) ^ (srow & 7);         // swizzled slot

    // hoist Q as B-frags: col q = lq, k d = kf*32 + g*8
    short8 qf[2];
#pragma unroll
    for (int kf = 0; kf < 2; ++kf)
        qf[kf] = *(const short8*)&Q[(size_t)(q0 + wid * 16 + lq) * DM + hc + kf * 32 + g * 8];

    f32x4 oacc[4];
    float lr = 0.f;                        // per-lane partial sum
#pragma unroll
    for (int nf = 0; nf < 4; ++nf) oacc[nf] = (f32x4){0.f, 0.f, 0.f, 0.f};

    // ---- prologue: issue tile tstart into buffer 0 (K and V^T) ----
    {
        const int k0 = tstart * 64;
#pragma unroll
        for (int u = 0; u < 2; ++u) {
            const int row = u * 32 + srow;
            gload16(K + (size_t)(k0 + row) * DM + hc + sss * 8,
                    (char*)Ks[0] + u * 4096 + wid * 1024);
            gload16(VT + (size_t)(hc + row) * SLEN + k0 + sss * 8,
                    (char*)Vt[0] + u * 4096 + wid * 1024);
        }
    }

    for (int t = tstart; t < tend; ++t) {
        const int cur = (t - tstart) & 1, nxt = cur ^ 1;
        const int k0 = t * 64;

        asm volatile("s_waitcnt vmcnt(0)" ::: "memory");   // my cur-tile loads done
        __builtin_amdgcn_s_barrier();                      // => all waves' loads done

        // nxt buffer provably dead now: issue next tile (lands under compute)
        if (t + 1 < tend) {
            const int k0n = k0 + 64;
#pragma unroll
            for (int u = 0; u < 2; ++u) {
                const int row = u * 32 + srow;
                gload16(K + (size_t)(k0n + row) * DM + hc + sss * 8,
                        (char*)Ks[nxt] + u * 4096 + wid * 1024);
                gload16(VT + (size_t)(hc + row) * SLEN + k0n + sss * 8,
                        (char*)Vt[nxt] + u * 4096 + wid * 1024);
            }
        }

        // S^T = K * Q^T : lane q = lq, kv = cf*16 + 4g + r
        f32x4 st[4];
#pragma unroll
        for (int cf = 0; cf < 4; ++cf) st[cf] = (f32x4){0.f, 0.f, 0.f, 0.f};

        __builtin_amdgcn_s_setprio(1);
#pragma unroll
        for (int cf = 0; cf < 4; ++cf) {
            const int row = cf * 16 + lq;
            const short8 ak0 = *(const short8*)((const char*)Ks[cur] + row * 128 + ((g)     ^ (row & 7)) * 16);
            const short8 ak1 = *(const short8*)((const char*)Ks[cur] + row * 128 + ((4 + g) ^ (row & 7)) * 16);
            st[cf] = __builtin_amdgcn_mfma_f32_16x16x32_bf16(ak0, qf[0], st[cf], 0, 0, 0);
            st[cf] = __builtin_amdgcn_mfma_f32_16x16x32_bf16(ak1, qf[1], st[cf], 0, 0, 0);
        }
        __builtin_amdgcn_s_setprio(0);

        // causal mask: only the global diagonal tile
        if (t == ntg - 1) {
            const int qg = q0 + wid * 16 + lq;
#pragma unroll
            for (int cf = 0; cf < 4; ++cf)
#pragma unroll
                for (int r = 0; r < 4; ++r)
                    if (k0 + cf * 16 + g * 4 + r > qg) st[cf][r] = -INFINITY;
        }

        // softmax: p = exp2(s) unscaled (2^m factor cancels in normalize)
#pragma unroll
        for (int cf = 0; cf < 4; ++cf)
#pragma unroll
            for (int r = 0; r < 4; ++r) {
                const float p = __builtin_amdgcn_exp2f(st[cf][r]);
                st[cf][r] = p;
                lr += p;
            }

        // pack P: wx[cf] = bf16pair(kv 16cf+4g+{0,1}), wy[cf] = (+{2,3})
        u32 wx[4], wy[4];
#pragma unroll
        for (int cf = 0; cf < 4; ++cf) {
            wx[cf] = cvtpk(st[cf][0], st[cf][1]);
            wy[cf] = cvtpk(st[cf][2], st[cf][3]);
        }

        // in-register P^T -> PV B-frag: 4x4 g-group transpose via permlane
        short8 pbf[2];
#pragma unroll
        for (int kf = 0; kf < 2; ++kf) {
            u32 x0 = wx[2 * kf], y0 = wx[2 * kf + 1];
            asm volatile("v_permlane32_swap_b32 %0, %1" : "+v"(x0), "+v"(y0));
            asm volatile("v_permlane16_swap_b32 %0, %1" : "+v"(x0), "+v"(y0));
            u32 x1 = wy[2 * kf], y1 = wy[2 * kf + 1];
            asm volatile("v_permlane32_swap_b32 %0, %1" : "+v"(x1), "+v"(y1));
            asm volatile("v_permlane16_swap_b32 %0, %1" : "+v"(x1), "+v"(y1));
            u32x4 bv;
            bv.x = x0; bv.y = x1; bv.z = y0; bv.w = y1;
            pbf[kf] = __builtin_bit_cast(short8, bv);
        }

        // O^T += V^T * P^T
        __builtin_amdgcn_s_setprio(1);
#pragma unroll
        for (int kf = 0; kf < 2; ++kf)
#pragma unroll
            for (int nf = 0; nf < 4; ++nf) {
                const int row = nf * 16 + lq;
                const short8 av = *(const short8*)((const char*)Vt[cur] + row * 128 + ((kf * 4 + g) ^ (row & 7)) * 16);
                oacc[nf] = __builtin_amdgcn_mfma_f32_16x16x32_bf16(av, pbf[kf], oacc[nf], 0, 0, 0);
            }
        __builtin_amdgcn_s_setprio(0);
    }

    // epilogue: reduce lr across the 4 g-groups once, then store
    lr += __shfl_xor(lr, 16, 64);
    lr += __shfl_xor(lr, 32, 64);
    const float inv = 1.0f / lr;
    const int qloc = wid * 16 + lq;
    if (pi < 0) {
        // direct: O = O^T / l -> A (bf16)
        const int qg = q0 + qloc;
#pragma unroll
        for (int nf = 0; nf < 4; ++nf) {
            u32x2 w;
            w.x = cvtpk(oacc[nf][0] * inv, oacc[nf][1] * inv);
            w.y = cvtpk(oacc[nf][2] * inv, oacc[nf][3] * inv);
            *(u32x2*)&A[(size_t)qg * DM + hc + nf * 16 + g * 4] = w;
        }
    } else {
        // split: normalized partial O (f16) + l
        u16* op = Opart + (size_t)pi * 4096 + qloc * 64;
#pragma unroll
        for (int nf = 0; nf < 4; ++nf) {
            u32x2 w;
            w.x = pkh2(oacc[nf][0] * inv, oacc[nf][1] * inv);
            w.y = pkh2(oacc[nf][2] * inv, oacc[nf][3] * inv);
            *(u32x2*)&op[nf * 16 + g * 4] = w;
        }
        if (g == 0) ML[pi * 64 + qloc] = lr;
    }
}

// ---------------------------------------------------------------------------
// combine: merge the 2 kv-chunk partials for qb in [32,63]. Same (implicit)
// max on both chunks -> weights are pure l-ratios.
// 384 blocks x 256 thr; thread = (q = tid>>2, 16 d's at (tid&3)*16).
// ---------------------------------------------------------------------------
__global__ __launch_bounds__(256)
void attn_combine(const u16* __restrict__ Opart, const float* __restrict__ ML,
                  u16* __restrict__ A)
{
    const int bi = blockIdx.x;
    const int qb = 32 + bi / NH, h = bi % NH;
    const int base = ((qb - 32) * NH + h) * 2;
    const int q = threadIdx.x >> 2, db = (threadIdx.x & 3) * 16;

    const float l0 = ML[base * 64 + q];
    const float l1 = ML[base * 64 + 64 + q];
    const float inv = 1.0f / (l0 + l1);
    const float w0 = l0 * inv, w1 = l1 * inv;

    const _Float16* O0 = (const _Float16*)(Opart + (size_t)base * 4096) + q * 64 + db;
    const _Float16* O1 = O0 + 4096;
    u16* dst = A + (size_t)(qb * 64 + q) * DM + h * DKH + db;

    u32 wbuf[8];
#pragma unroll
    for (int j = 0; j < 8; ++j) {
        const float v0 = w0 * (float)O0[2 * j]     + w1 * (float)O1[2 * j];
        const float v1 = w0 * (float)O0[2 * j + 1] + w1 * (float)O1[2 * j + 1];
        wbuf[j] = cvtpk(v0, v1);
    }
#pragma unroll
    for (int j = 0; j < 4; ++j)
        *(u32x2*)&dst[j * 4] = (u32x2){wbuf[2 * j], wbuf[2 * j + 1]};
}

extern "C" void kernel_launch(void* const* d_in, const int* in_sizes, int n_in,
                              void* d_out, int out_size, void* d_ws, size_t ws_size,
                              hipStream_t stream)
{
    const float* x  = (const float*)d_in[0];
    const float* wq = (const float*)d_in[1];
    const float* wk = (const float*)d_in[2];
    const float* wv = (const float*)d_in[3];
    const float* wo = (const float*)d_in[4];
    const int*  pos = (const int*)d_in[5];
    float* out = (float*)d_out;

    const size_t SD = (size_t)SLEN * DM;   // 3145728
    const size_t WW = (size_t)DM * DM;     // 589824
    if (ws_size < ((SD * 5 + WW * 4) * 2 + (size_t)SLEN * 32 * 8 + 1024)) return;

    u16* cx  = (u16*)d_ws;
    u16* cwq = cx  + SD;
    u16* cwk = cwq + WW;
    u16* cwv = cwk + WW;
    u16* cwo = cwv + WW;
    u16* qb_ = cwo + WW;
    u16* kb_ = qb_ + SD;
    u16* vb_ = kb_ + SD;     // V^T: [DM][SLEN]
    u16* ab_ = vb_ + SD;
    float2* tab = (float2*)(ab_ + SD);

    // partials reuse regions dead after gemm1: Opart in cx (exactly SD u16),
    // ML in cwq (768*64*4B = 196KB < WW*2B).
    u16*   opart = cx;
    float* ml    = (float*)cwq;

    prep_kernel<<<5888, 256, 0, stream>>>(x, wq, wk, wv, wo, pos,
                                          cx, cwq, cwk, cwv, cwo, tab);

    dim3 g1(SLEN / 64, DM / 128, 3);
    gemm_bf16<<<g1, 256, 0, stream>>>(cx, cwq, cwk, cwv, tab,
                                      qb_, kb_, vb_, nullptr, 0);

    attn_mfma<<<dim3(1152), 256, 0, stream>>>(qb_, kb_, vb_, ab_, opart, ml);
    attn_combine<<<dim3(384), 256, 0, stream>>>(opart, ml, ab_);

    dim3 g3(SLEN / 64, DM / 128, 1);
    gemm_bf16<<<g3, 256, 0, stream>>>(ab_, cwo, cwo, cwo, tab,
                                      nullptr, nullptr, nullptr, out, 3);
}